// Round 3
// baseline (334.190 us; speedup 1.0000x reference)
//
#include <hip/hip_runtime.h>
#include <hip/hip_bf16.h>

// Problem constants
#define Bc 2
#define Tc 2048
#define Cc 2048
#define Hc 16
#define Dc 128
#define BTc 4096
#define NQ 6144            // 3*Cc
#define EPSc 1e-5f
#define QSCALE 0.08838834764831845f   // 1/sqrt(128)

typedef __attribute__((ext_vector_type(8))) short bf16x8;
typedef __attribute__((ext_vector_type(4))) short bf16x4;
typedef __attribute__((ext_vector_type(4))) float f32x4;

__device__ __forceinline__ f32x4 mfma16(bf16x8 a, bf16x8 b, f32x4 c) {
  return __builtin_amdgcn_mfma_f32_16x16x32_bf16(a, b, c, 0, 0, 0);
}

__device__ __forceinline__ void gload16(const void* g, void* l) {
  __builtin_amdgcn_global_load_lds(
      (const __attribute__((address_space(1))) void*)g,
      (__attribute__((address_space(3))) void*)l, 16, 0, 0);
}

// ---------------- fp32 -> bf16 convert (x) ----------------
__global__ __launch_bounds__(256) void k_xconv(const float* __restrict__ x,
                                               __hip_bfloat16* __restrict__ xb) {
  size_t i = ((size_t)blockIdx.x * 256 + threadIdx.x) * 4;
  float4 v = *(const float4*)(x + i);
  union { __hip_bfloat16 h[4]; bf16x4 v4; } u;
  u.h[0] = __float2bfloat16(v.x); u.h[1] = __float2bfloat16(v.y);
  u.h[2] = __float2bfloat16(v.z); u.h[3] = __float2bfloat16(v.w);
  *(bf16x4*)(xb + i) = u.v4;
}

// ------- weight transpose+convert: W (K x N) fp32 -> Wt (N x K) bf16 -------
__global__ __launch_bounds__(256) void k_wconv(const float* __restrict__ Wq,
    const float* __restrict__ Wk, const float* __restrict__ Wv,
    const float* __restrict__ Wp, __hip_bfloat16* __restrict__ Wqkv_t,
    __hip_bfloat16* __restrict__ Wproj_t) {
  __shared__ float tile[64][65];
  int z = blockIdx.z;
  const float* src = (z == 0) ? Wq : (z == 1) ? Wk : (z == 2) ? Wv : Wp;
  __hip_bfloat16* dst = (z < 3) ? (Wqkv_t + (size_t)z * Cc * Cc) : Wproj_t;
  int k0 = blockIdx.x * 64, n0 = blockIdx.y * 64;
  int c = threadIdx.x & 63, rb = threadIdx.x >> 6;
  for (int i = 0; i < 16; i++) {
    int r = rb * 16 + i;
    tile[r][c] = src[(size_t)(k0 + r) * Cc + n0 + c];
  }
  __syncthreads();
  for (int i = 0; i < 16; i++) {
    int r = rb * 16 + i;
    dst[(size_t)(n0 + r) * Cc + k0 + c] = __float2bfloat16(tile[c][r]);
  }
}

// ============ 256x256 8-phase GEMM (T1+T2+T3+T4+T5), B pre-transposed ======
// C[m][n] = sum_k A[m][k] * Bt[n][k].  8 waves (2Mx4N), BK=64, LDS ring of
// 8 half-slots (16KB each): slot h%8 holds half h; halves per K-tile t:
// [A k0, B k0, A k1, B k1].  Each phase: read 1 slot -> regs, stage 1 half
// (2 x global_load_lds) into slot read 2 phases ago, barrier, lgkmcnt(0),
// 16 MFMA, barrier.  vmcnt(6) at phases 4,8 covers next tile exactly.
__device__ __forceinline__ void read_a8(bf16x8 (&dst)[8], const char* lds, int off) {
#pragma unroll
  for (int m = 0; m < 8; m++)
    dst[m] = *(const bf16x8*)(lds + off + m * 1024);
}
__device__ __forceinline__ void read_b4(bf16x8 (&dst)[4], const char* lds, int off) {
#pragma unroll
  for (int n = 0; n < 4; n++)
    dst[n] = *(const bf16x8*)(lds + off + n * 1024);
}
template <int MH>
__device__ __forceinline__ void mm16(f32x4 (&acc)[8][4], const bf16x8 (&X)[8],
                                     const bf16x8 (&Y)[4]) {
  __builtin_amdgcn_s_setprio(1);
#pragma unroll
  for (int m = 0; m < 4; m++)
#pragma unroll
    for (int n = 0; n < 4; n++)
      acc[MH * 4 + m][n] = mfma16(X[MH * 4 + m], Y[n], acc[MH * 4 + m][n]);
  __builtin_amdgcn_s_setprio(0);
}

template <typename OutT>
__global__ __launch_bounds__(512, 2) void k_gemm8(const __hip_bfloat16* __restrict__ A,
    const __hip_bfloat16* __restrict__ Bt, OutT* __restrict__ Co,
    int M, int N, int K) {
  __shared__ __align__(16) char lds[131072];
  const int nbx = M >> 8;
  const int nwg = nbx * (N >> 8);              // divisible by 8 for our shapes
  const int wg = blockIdx.x;
  const int swz = (wg & 7) * (nwg >> 3) + (wg >> 3);
  const int bx = swz % nbx, by = swz / nbx;
  const int tid = threadIdx.x, lane = tid & 63, wid = tid >> 6;
  const int wr = wid >> 2, wc = wid & 3;
  const int lr = lane & 15, lg = lane >> 4;
  // swizzled read offsets: chunk selector lg ^ ((row>>1)&3), row%16 == lr
  const int xs = lg ^ ((lr >> 1) & 3);
  const int aoff = (wr * 128 + lr) * 64 + xs * 16;   // + m*1024
  const int boff = (wc * 64 + lr) * 64 + xs * 16;    // + n*1024
  // staging: thread covers rows srow and srow+128 at swizzled source column
  const int srow = wid * 16 + (lane >> 2);
  const int scol = (((lane & 3) ^ ((srow >> 1) & 3)) << 3);
  const __hip_bfloat16* Ag = A + (size_t)(bx * 256 + srow) * K + scol;
  const __hip_bfloat16* Bg = Bt + (size_t)(by * 256 + srow) * K + scol;
  char* ldsw = lds + wid * 1024;
  const size_t rstep = (size_t)128 * K;

#define STG_A(slot, t, ks) { const __hip_bfloat16* g_ = Ag + (t) * 64 + (ks) * 32; \
    gload16(g_, ldsw + (slot) * 16384);                                            \
    gload16(g_ + rstep, ldsw + (slot) * 16384 + 8192); }
#define STG_B(slot, t, ks) { const __hip_bfloat16* g_ = Bg + (t) * 64 + (ks) * 32; \
    gload16(g_, ldsw + (slot) * 16384);                                            \
    gload16(g_ + rstep, ldsw + (slot) * 16384 + 8192); }
#define BARRIER __builtin_amdgcn_s_barrier()
#define VW6 asm volatile("s_waitcnt vmcnt(6)" ::: "memory")
#define LGKM0 asm volatile("s_waitcnt lgkmcnt(0)" ::: "memory")

  f32x4 acc[8][4];
#pragma unroll
  for (int m = 0; m < 8; m++)
#pragma unroll
    for (int n = 0; n < 4; n++) acc[m][n] = f32x4{0.f, 0.f, 0.f, 0.f};
  bf16x8 rA0[8], rA1[8], rB0[4], rB1[4];

  const int NT = K >> 6, NIT = K >> 7;   // NT even
  // prologue: tile0 fully (slots 0-3), tile1 h1-h3 (slots 4-6)
  STG_A(0, 0, 0); STG_B(1, 0, 0); STG_A(2, 0, 1); STG_B(3, 0, 1);
  STG_A(4, 1, 0); STG_B(5, 1, 0); STG_A(6, 1, 1);
  asm volatile("s_waitcnt vmcnt(6)" ::: "memory");
  BARRIER;

  for (int it = 0; it < NIT; ++it) {
    const int t1 = 2 * it + 1;
    const int t2 = (2 * it + 2 < NT) ? 2 * it + 2 : NT - 1;  // clamped (last iter)
    const int t3 = (2 * it + 3 < NT) ? 2 * it + 3 : NT - 1;
    // ph1: read A(t0,k0) slot0; stage B(t1,k1)->slot7; MFMA (t_prev1,k1) m0-3
    read_a8(rA0, lds, 0 * 16384 + aoff);
    STG_B(7, t1, 1);
    BARRIER; LGKM0;
    if (it) mm16<0>(acc, rA1, rB1);
    BARRIER;
    // ph2: read B(t0,k0) slot1; stage A(t2,k0)->slot0; MFMA (t_prev1,k1) m4-7
    read_b4(rB0, lds, 1 * 16384 + boff);
    STG_A(0, t2, 0);
    BARRIER; LGKM0;
    if (it) mm16<1>(acc, rA1, rB1);
    BARRIER;
    // ph3: read A(t0,k1) slot2; stage B(t2,k0)->slot1; MFMA (t0,k0) m0-3
    read_a8(rA1, lds, 2 * 16384 + aoff);
    STG_B(1, t2, 0);
    BARRIER; LGKM0;
    mm16<0>(acc, rA0, rB0);
    BARRIER;
    // ph4: read B(t0,k1) slot3; stage A(t2,k1)->slot2; vmcnt(6); MFMA (t0,k0) m4-7
    read_b4(rB1, lds, 3 * 16384 + boff);
    STG_A(2, t2, 1);
    VW6;
    BARRIER; LGKM0;
    mm16<1>(acc, rA0, rB0);
    BARRIER;
    // ph5: read A(t1,k0) slot4; stage B(t2,k1)->slot3; MFMA (t0,k1) m0-3
    read_a8(rA0, lds, 4 * 16384 + aoff);
    STG_B(3, t2, 1);
    BARRIER; LGKM0;
    mm16<0>(acc, rA1, rB1);
    BARRIER;
    // ph6: read B(t1,k0) slot5; stage A(t3,k0)->slot4; MFMA (t0,k1) m4-7
    read_b4(rB0, lds, 5 * 16384 + boff);
    STG_A(4, t3, 0);
    BARRIER; LGKM0;
    mm16<1>(acc, rA1, rB1);
    BARRIER;
    // ph7: read A(t1,k1) slot6; stage B(t3,k0)->slot5; MFMA (t1,k0) m0-3
    read_a8(rA1, lds, 6 * 16384 + aoff);
    STG_B(5, t3, 0);
    BARRIER; LGKM0;
    mm16<0>(acc, rA0, rB0);
    BARRIER;
    // ph8: read B(t1,k1) slot7; stage A(t3,k1)->slot6; vmcnt(6); MFMA (t1,k0) m4-7
    read_b4(rB1, lds, 7 * 16384 + boff);
    STG_A(6, t3, 1);
    VW6;
    BARRIER; LGKM0;
    mm16<1>(acc, rA0, rB0);
    BARRIER;
  }
  // drain: (t_{NT-1}, k1)
  mm16<0>(acc, rA1, rB1);
  mm16<1>(acc, rA1, rB1);
#undef STG_A
#undef STG_B

  const int row0 = bx * 256 + wr * 128 + lg * 4;
  const int col0 = by * 256 + wc * 64 + lr;
#pragma unroll
  for (int m = 0; m < 8; m++)
#pragma unroll
    for (int n = 0; n < 4; n++) {
      size_t base = (size_t)(row0 + m * 16) * N + col0 + n * 16;
#pragma unroll
      for (int r = 0; r < 4; r++) {
        float v = acc[m][n][r];
        if constexpr (sizeof(OutT) == 2)
          Co[base + (size_t)r * N] = __float2bfloat16(v);
        else
          Co[base + (size_t)r * N] = v;
      }
    }
}

// ---------------- in-place QK RMSNorm over head dim (D=128) ----------------
__global__ __launch_bounds__(256) void k_qkrms(__hip_bfloat16* __restrict__ QKV,
    const float* __restrict__ qw, const float* __restrict__ kw) {
  int bt = blockIdx.x;
  int w = threadIdx.x >> 6, lane = threadIdx.x & 63;
  int hv = blockIdx.y * 4 + w;
  const float* wt; int col; float extra;
  if (hv < 16) { wt = qw; col = hv * Dc;             extra = QSCALE; }
  else         { wt = kw; col = Cc + (hv - 16) * Dc; extra = 1.0f;   }
  __hip_bfloat16* p = QKV + (size_t)bt * NQ + col + lane * 2;
  float x0 = __bfloat162float(p[0]);
  float x1 = __bfloat162float(p[1]);
  float ss = x0 * x0 + x1 * x1;
  for (int m = 1; m < 64; m <<= 1) ss += __shfl_xor(ss, m);
  float sc = rsqrtf(ss * (1.0f / Dc) + EPSc) * extra;
  p[0] = __float2bfloat16(x0 * sc * wt[lane * 2]);
  p[1] = __float2bfloat16(x1 * sc * wt[lane * 2 + 1]);
}

// ---------------- V transpose: (b,t,h,d) cols of QKV -> Vt (b,h,d,t) -------
__global__ __launch_bounds__(256) void k_vtrans(const __hip_bfloat16* __restrict__ QKV,
                                                __hip_bfloat16* __restrict__ Vt) {
  __shared__ __hip_bfloat16 tile[64][65];
  int bh = blockIdx.z, t0 = blockIdx.x * 64, d0 = blockIdx.y * 64;
  int b = bh >> 4, h = bh & 15;
  int c = threadIdx.x & 63, rb = threadIdx.x >> 6;
  for (int i = 0; i < 16; i++) {
    int r = rb * 16 + i;
    tile[r][c] = QKV[(size_t)(b * Tc + t0 + r) * NQ + 2 * Cc + h * Dc + d0 + c];
  }
  __syncthreads();
  for (int i = 0; i < 16; i++) {
    int r = rb * 16 + i;
    Vt[((size_t)bh * Dc + d0 + r) * Tc + t0 + c] = tile[c][r];
  }
}

// ---------------- flash attention v2: LDS-staged K/V, dbuf, paired tiles ---
// grid (bh=32, pp=16); 4 waves; block handles q-tiles {31-pp, pp} (64 rows each)
__global__ __launch_bounds__(256, 2) void k_attn(const __hip_bfloat16* __restrict__ QKV,
    const __hip_bfloat16* __restrict__ Vt, const float* __restrict__ subw,
    __hip_bfloat16* __restrict__ Y) {
  __shared__ __align__(16) __hip_bfloat16 Ks[2][64][128];   // 32 KB
  __shared__ __align__(16) __hip_bfloat16 Vs[2][128][64];   // 32 KB
  __shared__ __align__(16) __hip_bfloat16 Plds[4][16][72];  // 9 KB (padded stride 144B)
  const int bh = blockIdx.x, pp = blockIdx.y;
  const int b = bh >> 4, h = bh & 15;
  const int w = threadIdx.x >> 6, lane = threadIdx.x & 63;
  const int lr = lane & 15, lg = lane >> 4;
  const float slope = exp2f(-0.5f * (float)(h + 1));
  const __hip_bfloat16* Kbase = QKV + (size_t)b * Tc * NQ + Cc + h * Dc;
  const __hip_bfloat16* Vbase = Vt + (size_t)bh * Dc * Tc;
  const int krow = (lane >> 4);
  const int kcolb = ((lane & 15) << 4);
  const int vrow = (lane >> 3);
  const int vcolb = ((lane & 7) << 4);
  f32x4 zero = {0.f, 0.f, 0.f, 0.f};

  int buf = 0;
  for (int ti = 0; ti < 2; ti++) {
    const int qt = (ti == 0) ? (31 - pp) : pp;
    const int q0 = qt * 64 + w * 16;
    const int nchunk = qt + 1;
    bf16x8 aq[4];
    {
      const __hip_bfloat16* qb = QKV + (size_t)(b * Tc + q0 + lr) * NQ + h * Dc + lg * 8;
      for (int c = 0; c < 4; c++) aq[c] = *(const bf16x8*)(qb + c * 32);
    }
    f32x4 acc[8];
    for (int d = 0; d < 8; d++) acc[d] = zero;
    float mrow[4] = {-1e30f, -1e30f, -1e30f, -1e30f};
    float lrow[4] = {0.f, 0.f, 0.f, 0.f};

#define STAGE(bb, t)                                                              \
    {                                                                             \
      const int s0_ = (t) * 64;                                                   \
      for (int j = 0; j < 4; j++) {                                               \
        int row = w * 16 + j * 4 + krow;                                          \
        int cb = kcolb ^ ((row & 7) << 4);                                        \
        gload16(Kbase + (size_t)(s0_ + row) * NQ + (cb >> 1),                     \
                &Ks[bb][w * 16 + j * 4][0]);                                      \
      }                                                                           \
      for (int j = 0; j < 4; j++) {                                               \
        int row = w * 32 + j * 8 + vrow;                                          \
        int cb = vcolb ^ ((row & 7) << 4);                                        \
        gload16(Vbase + (size_t)row * Tc + s0_ + (cb >> 1),                       \
                &Vs[bb][w * 32 + j * 8][0]);                                      \
      }                                                                           \
    }

    STAGE(buf, 0);
    __syncthreads();
    for (int t = 0; t < nchunk; t++) {
      if (t + 1 < nchunk) STAGE(buf ^ 1, t + 1);
      const int s0 = t * 64;
      f32x4 s[4];
      for (int ss = 0; ss < 4; ss++) s[ss] = zero;
      __builtin_amdgcn_s_setprio(1);
      for (int c = 0; c < 4; c++)
        for (int ss = 0; ss < 4; ss++) {
          int kr = ss * 16 + lr;
          const bf16x8 kf = *(const bf16x8*)
              &Ks[buf][kr][((c * 64 + lg * 16) ^ ((kr & 7) << 4)) >> 1];
          s[ss] = mfma16(aq[c], kf, s[ss]);
        }
      __builtin_amdgcn_s_setprio(0);
      float ps[4][4], mt[4];
      for (int r = 0; r < 4; r++) mt[r] = -1e30f;
      for (int ss = 0; ss < 4; ss++) {
        int jj = s0 + ss * 16 + lr;
        for (int r = 0; r < 4; r++) {
          int i = q0 + lg * 4 + r;
          float pv = (jj <= i) ? s[ss][r] - slope * (float)(i - jj) : -1e30f;
          ps[ss][r] = pv;
          mt[r] = fmaxf(mt[r], pv);
        }
      }
      for (int m = 1; m < 16; m <<= 1)
        for (int r = 0; r < 4; r++) mt[r] = fmaxf(mt[r], __shfl_xor(mt[r], m));
      float corr[4], rs[4];
      for (int r = 0; r < 4; r++) {
        float mn = fmaxf(mrow[r], mt[r]);
        corr[r] = __expf(mrow[r] - mn);
        mrow[r] = mn;
        rs[r] = 0.f;
      }
      for (int ss = 0; ss < 4; ss++)
        for (int r = 0; r < 4; r++) {
          float e = __expf(ps[ss][r] - mrow[r]);
          ps[ss][r] = e;
          rs[r] += e;
        }
      for (int m = 1; m < 16; m <<= 1)
        for (int r = 0; r < 4; r++) rs[r] += __shfl_xor(rs[r], m);
      for (int r = 0; r < 4; r++) lrow[r] = lrow[r] * corr[r] + rs[r];
      for (int d = 0; d < 8; d++)
        for (int r = 0; r < 4; r++) acc[d][r] *= corr[r];
      for (int ss = 0; ss < 4; ss++)
        for (int r = 0; r < 4; r++)
          Plds[w][lg * 4 + r][ss * 16 + lr] = __float2bfloat16(ps[ss][r]);
      bf16x8 pa0 = *(const bf16x8*)&Plds[w][lr][lg * 8];
      bf16x8 pa1 = *(const bf16x8*)&Plds[w][lr][32 + lg * 8];
      __builtin_amdgcn_s_setprio(1);
      for (int d = 0; d < 8; d++) {
        int vr = d * 16 + lr;
        const bf16x8 b0 = *(const bf16x8*)
            &Vs[buf][vr][((lg * 16) ^ ((vr & 7) << 4)) >> 1];
        const bf16x8 b1 = *(const bf16x8*)
            &Vs[buf][vr][((64 + lg * 16) ^ ((vr & 7) << 4)) >> 1];
        acc[d] = mfma16(pa0, b0, acc[d]);
        acc[d] = mfma16(pa1, b1, acc[d]);
      }
      __builtin_amdgcn_s_setprio(0);
      __syncthreads();
      buf ^= 1;
    }
#undef STAGE
    float ssum[4] = {0.f, 0.f, 0.f, 0.f};
    for (int r = 0; r < 4; r++) {
      float rl = 1.0f / lrow[r];
      for (int d = 0; d < 8; d++) {
        float o = acc[d][r] * rl;
        acc[d][r] = o;
        ssum[r] += o * o;
      }
    }
    for (int m = 1; m < 16; m <<= 1)
      for (int r = 0; r < 4; r++) ssum[r] += __shfl_xor(ssum[r], m);
    float ms[4];
    for (int r = 0; r < 4; r++) ms[r] = rsqrtf(ssum[r] * (1.0f / Dc) + EPSc);
    for (int d = 0; d < 8; d++) {
      float wv = subw[d * 16 + lr];
      for (int r = 0; r < 4; r++) {
        float y = acc[d][r] * ms[r] * wv;
        Y[(size_t)(b * Tc + q0 + lg * 4 + r) * Cc + h * Dc + d * 16 + lr] =
            __float2bfloat16(y);
      }
    }
  }
}

extern "C" void kernel_launch(void* const* d_in, const int* in_sizes, int n_in,
                              void* d_out, int out_size, void* d_ws, size_t ws_size,
                              hipStream_t stream) {
  const float* x  = (const float*)d_in[0];
  const float* Wq = (const float*)d_in[1];
  const float* Wk = (const float*)d_in[2];
  const float* Wv = (const float*)d_in[3];
  const float* Wp = (const float*)d_in[4];
  const float* qw = (const float*)d_in[5];
  const float* kw = (const float*)d_in[6];
  const float* sw = (const float*)d_in[7];
  float* out = (float*)d_out;

  char* ws = (char*)d_ws;
  __hip_bfloat16* Xb    = (__hip_bfloat16*)(ws + 0);          // 16 MiB (4096x2048)
  __hip_bfloat16* Wqkv  = (__hip_bfloat16*)(ws + 16777216);   // 24 MiB (6144x2048, N-major)
  __hip_bfloat16* Wproj = (__hip_bfloat16*)(ws + 41943040);   //  8 MiB (2048x2048, N-major)
  __hip_bfloat16* QKV   = (__hip_bfloat16*)(ws + 50331648);   // 48 MiB (4096x6144)
  __hip_bfloat16* Vt    = (__hip_bfloat16*)(ws + 100663296);  // 16 MiB (b,h,d,t)
  __hip_bfloat16* Yb    = (__hip_bfloat16*)(ws + 117440512);  // 16 MiB (4096x2048)

  k_xconv<<<dim3((BTc * Cc) / 1024), 256, 0, stream>>>(x, Xb);
  k_wconv<<<dim3(32, 32, 4), 256, 0, stream>>>(Wq, Wk, Wv, Wp, Wqkv, Wproj);
  k_gemm8<__hip_bfloat16><<<dim3((BTc / 256) * (NQ / 256)), 512, 0, stream>>>(
      Xb, Wqkv, QKV, BTc, NQ, Cc);
  k_qkrms<<<dim3(BTc, 8), 256, 0, stream>>>(QKV, qw, kw);
  k_vtrans<<<dim3(Tc / 64, Dc / 64, Bc * Hc), 256, 0, stream>>>(QKV, Vt);
  k_attn<<<dim3(Bc * Hc, 16), 256, 0, stream>>>(QKV, Vt, sw, Yb);
  k_gemm8<float><<<dim3((BTc / 256) * (Cc / 256)), 512, 0, stream>>>(
      Yb, Wproj, out, BTc, Cc, Cc);
}

// Round 4
// 320.215 us; speedup vs baseline: 1.0436x; 1.0436x over previous
//
#include <hip/hip_runtime.h>
#include <hip/hip_bf16.h>

// Problem constants
#define Bc 2
#define Tc 2048
#define Cc 2048
#define Hc 16
#define Dc 128
#define BTc 4096
#define NQ 6144            // 3*Cc
#define EPSc 1e-5f
#define QSCALE 0.08838834764831845f   // 1/sqrt(128)

typedef __attribute__((ext_vector_type(8))) short bf16x8;
typedef __attribute__((ext_vector_type(4))) short bf16x4;
typedef __attribute__((ext_vector_type(4))) float f32x4;

__device__ __forceinline__ f32x4 mfma16(bf16x8 a, bf16x8 b, f32x4 c) {
  return __builtin_amdgcn_mfma_f32_16x16x32_bf16(a, b, c, 0, 0, 0);
}

__device__ __forceinline__ void gload16(const void* g, void* l) {
  __builtin_amdgcn_global_load_lds(
      (const __attribute__((address_space(1))) void*)g,
      (__attribute__((address_space(3))) void*)l, 16, 0, 0);
}

// ---------------- fp32 -> bf16 convert (x) ----------------
__global__ __launch_bounds__(256) void k_xconv(const float* __restrict__ x,
                                               __hip_bfloat16* __restrict__ xb) {
  size_t i = ((size_t)blockIdx.x * 256 + threadIdx.x) * 4;
  float4 v = *(const float4*)(x + i);
  union { __hip_bfloat16 h[4]; bf16x4 v4; } u;
  u.h[0] = __float2bfloat16(v.x); u.h[1] = __float2bfloat16(v.y);
  u.h[2] = __float2bfloat16(v.z); u.h[3] = __float2bfloat16(v.w);
  *(bf16x4*)(xb + i) = u.v4;
}

// ------- weight transpose+convert: W (K x N) fp32 -> Wt (N x K) bf16 -------
__global__ __launch_bounds__(256) void k_wconv(const float* __restrict__ Wq,
    const float* __restrict__ Wk, const float* __restrict__ Wv,
    const float* __restrict__ Wp, __hip_bfloat16* __restrict__ Wqkv_t,
    __hip_bfloat16* __restrict__ Wproj_t) {
  __shared__ float tile[64][65];
  int z = blockIdx.z;
  const float* src = (z == 0) ? Wq : (z == 1) ? Wk : (z == 2) ? Wv : Wp;
  __hip_bfloat16* dst = (z < 3) ? (Wqkv_t + (size_t)z * Cc * Cc) : Wproj_t;
  int k0 = blockIdx.x * 64, n0 = blockIdx.y * 64;
  int c = threadIdx.x & 63, rb = threadIdx.x >> 6;
  for (int i = 0; i < 16; i++) {
    int r = rb * 16 + i;
    tile[r][c] = src[(size_t)(k0 + r) * Cc + n0 + c];
  }
  __syncthreads();
  for (int i = 0; i < 16; i++) {
    int r = rb * 16 + i;
    dst[(size_t)(n0 + r) * Cc + k0 + c] = __float2bfloat16(tile[c][r]);
  }
}

// ============ 256x256 8-phase GEMM (T1+T2+T3+T4+T5), B pre-transposed ======
// C[m][n] = sum_k A[m][k] * Bt[n][k].  8 waves (2Mx4N), BK=64, LDS ring of
// 8 half-slots (16KB each).  Consume-lag-2 pipeline: phase i reads the
// fragments for the MFMA of phase i+2.  One barrier per phase; the
// lgkmcnt(0) drain sits AFTER the MFMA cluster (reads serviced under MFMA);
// compiler inserts counted lgkm waits for the lag-2 operands (already done).
// vmcnt(6) at phases 4,8 covers the gload->read lag exactly (verified:
// ph8's vmcnt covers stages prev-ph2..prev-ph5 -> slots read ph1-4;
// ph4's covers prev-ph6..this-ph1 -> slots read ph5-8).
__device__ __forceinline__ void read_a8(bf16x8 (&dst)[8], const char* lds, int off) {
#pragma unroll
  for (int m = 0; m < 8; m++)
    dst[m] = *(const bf16x8*)(lds + off + m * 1024);
}
__device__ __forceinline__ void read_b4(bf16x8 (&dst)[4], const char* lds, int off) {
#pragma unroll
  for (int n = 0; n < 4; n++)
    dst[n] = *(const bf16x8*)(lds + off + n * 1024);
}
template <int MH>
__device__ __forceinline__ void mm16(f32x4 (&acc)[8][4], const bf16x8 (&X)[8],
                                     const bf16x8 (&Y)[4]) {
  __builtin_amdgcn_s_setprio(1);
#pragma unroll
  for (int m = 0; m < 4; m++)
#pragma unroll
    for (int n = 0; n < 4; n++)
      acc[MH * 4 + m][n] = mfma16(X[MH * 4 + m], Y[n], acc[MH * 4 + m][n]);
  __builtin_amdgcn_s_setprio(0);
}

template <typename OutT>
__global__ __launch_bounds__(512, 2) void k_gemm8(const __hip_bfloat16* __restrict__ A,
    const __hip_bfloat16* __restrict__ Bt, OutT* __restrict__ Co,
    int M, int N, int K) {
  __shared__ __align__(16) char lds[131072];
  const int nbx = M >> 8;
  const int nwg = nbx * (N >> 8);              // divisible by 8 for our shapes
  const int wg = blockIdx.x;
  const int swz = (wg & 7) * (nwg >> 3) + (wg >> 3);
  const int bx = swz % nbx, by = swz / nbx;
  const int tid = threadIdx.x, lane = tid & 63, wid = tid >> 6;
  const int wr = wid >> 2, wc = wid & 3;
  const int lr = lane & 15, lg = lane >> 4;
  // swizzled read offsets: chunk selector lg ^ ((row>>1)&3), row%16 == lr
  const int xs = lg ^ ((lr >> 1) & 3);
  const int aoff = (wr * 128 + lr) * 64 + xs * 16;   // + m*1024
  const int boff = (wc * 64 + lr) * 64 + xs * 16;    // + n*1024
  // staging: thread covers rows srow and srow+128 at swizzled source column
  const int srow = wid * 16 + (lane >> 2);
  const int scol = (((lane & 3) ^ ((srow >> 1) & 3)) << 3);
  const __hip_bfloat16* Ag = A + (size_t)(bx * 256 + srow) * K + scol;
  const __hip_bfloat16* Bg = Bt + (size_t)(by * 256 + srow) * K + scol;
  char* ldsw = lds + wid * 1024;
  const size_t rstep = (size_t)128 * K;

#define STG_A(slot, t, ks) { const __hip_bfloat16* g_ = Ag + (t) * 64 + (ks) * 32; \
    gload16(g_, ldsw + (slot) * 16384);                                            \
    gload16(g_ + rstep, ldsw + (slot) * 16384 + 8192); }
#define STG_B(slot, t, ks) { const __hip_bfloat16* g_ = Bg + (t) * 64 + (ks) * 32; \
    gload16(g_, ldsw + (slot) * 16384);                                            \
    gload16(g_ + rstep, ldsw + (slot) * 16384 + 8192); }
#define BARRIER __builtin_amdgcn_s_barrier()
#define VW6 asm volatile("s_waitcnt vmcnt(6)" ::: "memory")
#define LGKM0 asm volatile("s_waitcnt lgkmcnt(0)" ::: "memory")
#define SB0 __builtin_amdgcn_sched_barrier(0)

  f32x4 acc[8][4];
#pragma unroll
  for (int m = 0; m < 8; m++)
#pragma unroll
    for (int n = 0; n < 4; n++) acc[m][n] = f32x4{0.f, 0.f, 0.f, 0.f};
  bf16x8 rA0[8], rA1[8], rB0[4], rB1[4];

  const int NT = K >> 6, NIT = K >> 7;   // NT even
  // prologue: tile0 fully (slots 0-3), tile1 h1-h3 (slots 4-6)
  STG_A(0, 0, 0); STG_B(1, 0, 0); STG_A(2, 0, 1); STG_B(3, 0, 1);
  STG_A(4, 1, 0); STG_B(5, 1, 0); STG_A(6, 1, 1);
  asm volatile("s_waitcnt vmcnt(6)" ::: "memory");
  BARRIER;

  for (int it = 0; it < NIT; ++it) {
    const int t1 = 2 * it + 1;
    const int t2 = (2 * it + 2 < NT) ? 2 * it + 2 : NT - 1;  // clamped (last iter)
    const int t3 = (2 * it + 3 < NT) ? 2 * it + 3 : NT - 1;
    // ph1: read A(t0,k0) slot0; stage B(t1,k1)->slot7; MFMA (t_prev,k1) m0-3
    read_a8(rA0, lds, 0 * 16384 + aoff);
    STG_B(7, t1, 1);
    if (it) mm16<0>(acc, rA1, rB1);
    SB0; LGKM0; BARRIER;
    // ph2: read B(t0,k0) slot1; stage A(t2,k0)->slot0; MFMA (t_prev,k1) m4-7
    read_b4(rB0, lds, 1 * 16384 + boff);
    STG_A(0, t2, 0);
    if (it) mm16<1>(acc, rA1, rB1);
    SB0; LGKM0; BARRIER;
    // ph3: read A(t0,k1) slot2; stage B(t2,k0)->slot1; MFMA (t0,k0) m0-3
    read_a8(rA1, lds, 2 * 16384 + aoff);
    STG_B(1, t2, 0);
    mm16<0>(acc, rA0, rB0);
    SB0; LGKM0; BARRIER;
    // ph4: read B(t0,k1) slot3; stage A(t2,k1)->slot2; MFMA (t0,k0) m4-7; vmcnt(6)
    read_b4(rB1, lds, 3 * 16384 + boff);
    STG_A(2, t2, 1);
    mm16<1>(acc, rA0, rB0);
    SB0; LGKM0; VW6; BARRIER;
    // ph5: read A(t1,k0) slot4; stage B(t2,k1)->slot3; MFMA (t0,k1) m0-3
    read_a8(rA0, lds, 4 * 16384 + aoff);
    STG_B(3, t2, 1);
    mm16<0>(acc, rA1, rB1);
    SB0; LGKM0; BARRIER;
    // ph6: read B(t1,k0) slot5; stage A(t3,k0)->slot4; MFMA (t0,k1) m4-7
    read_b4(rB0, lds, 5 * 16384 + boff);
    STG_A(4, t3, 0);
    mm16<1>(acc, rA1, rB1);
    SB0; LGKM0; BARRIER;
    // ph7: read A(t1,k1) slot6; stage B(t3,k0)->slot5; MFMA (t1,k0) m0-3
    read_a8(rA1, lds, 6 * 16384 + aoff);
    STG_B(5, t3, 0);
    mm16<0>(acc, rA0, rB0);
    SB0; LGKM0; BARRIER;
    // ph8: read B(t1,k1) slot7; stage A(t3,k1)->slot6; MFMA (t1,k0) m4-7; vmcnt(6)
    read_b4(rB1, lds, 7 * 16384 + boff);
    STG_A(6, t3, 1);
    mm16<1>(acc, rA0, rB0);
    SB0; LGKM0; VW6; BARRIER;
  }
  // drain: (t_{NT-1}, k1)
  mm16<0>(acc, rA1, rB1);
  mm16<1>(acc, rA1, rB1);
#undef STG_A
#undef STG_B

  const int row0 = bx * 256 + wr * 128 + lg * 4;
  const int col0 = by * 256 + wc * 64 + lr;
#pragma unroll
  for (int m = 0; m < 8; m++)
#pragma unroll
    for (int n = 0; n < 4; n++) {
      size_t base = (size_t)(row0 + m * 16) * N + col0 + n * 16;
#pragma unroll
      for (int r = 0; r < 4; r++) {
        float v = acc[m][n][r];
        if constexpr (sizeof(OutT) == 2)
          Co[base + (size_t)r * N] = __float2bfloat16(v);
        else
          Co[base + (size_t)r * N] = v;
      }
    }
}

// ---------------- in-place QK RMSNorm over head dim (D=128) ----------------
__global__ __launch_bounds__(256) void k_qkrms(__hip_bfloat16* __restrict__ QKV,
    const float* __restrict__ qw, const float* __restrict__ kw) {
  int bt = blockIdx.x;
  int w = threadIdx.x >> 6, lane = threadIdx.x & 63;
  int hv = blockIdx.y * 4 + w;
  const float* wt; int col; float extra;
  if (hv < 16) { wt = qw; col = hv * Dc;             extra = QSCALE; }
  else         { wt = kw; col = Cc + (hv - 16) * Dc; extra = 1.0f;   }
  __hip_bfloat16* p = QKV + (size_t)bt * NQ + col + lane * 2;
  float x0 = __bfloat162float(p[0]);
  float x1 = __bfloat162float(p[1]);
  float ss = x0 * x0 + x1 * x1;
  for (int m = 1; m < 64; m <<= 1) ss += __shfl_xor(ss, m);
  float sc = rsqrtf(ss * (1.0f / Dc) + EPSc) * extra;
  p[0] = __float2bfloat16(x0 * sc * wt[lane * 2]);
  p[1] = __float2bfloat16(x1 * sc * wt[lane * 2 + 1]);
}

// ---------------- V transpose: (b,t,h,d) cols of QKV -> Vt (b,h,d,t) -------
__global__ __launch_bounds__(256) void k_vtrans(const __hip_bfloat16* __restrict__ QKV,
                                                __hip_bfloat16* __restrict__ Vt) {
  __shared__ __hip_bfloat16 tile[64][65];
  int bh = blockIdx.z, t0 = blockIdx.x * 64, d0 = blockIdx.y * 64;
  int b = bh >> 4, h = bh & 15;
  int c = threadIdx.x & 63, rb = threadIdx.x >> 6;
  for (int i = 0; i < 16; i++) {
    int r = rb * 16 + i;
    tile[r][c] = QKV[(size_t)(b * Tc + t0 + r) * NQ + 2 * Cc + h * Dc + d0 + c];
  }
  __syncthreads();
  for (int i = 0; i < 16; i++) {
    int r = rb * 16 + i;
    Vt[((size_t)bh * Dc + d0 + r) * Tc + t0 + c] = tile[c][r];
  }
}

// ---------------- flash attention v2: LDS-staged K/V, dbuf, paired tiles ---
// grid (bh=32, pp=16); 4 waves; block handles q-tiles {31-pp, pp} (64 rows each)
__global__ __launch_bounds__(256, 2) void k_attn(const __hip_bfloat16* __restrict__ QKV,
    const __hip_bfloat16* __restrict__ Vt, const float* __restrict__ subw,
    __hip_bfloat16* __restrict__ Y) {
  __shared__ __align__(16) __hip_bfloat16 Ks[2][64][128];   // 32 KB
  __shared__ __align__(16) __hip_bfloat16 Vs[2][128][64];   // 32 KB
  __shared__ __align__(16) __hip_bfloat16 Plds[4][16][72];  // 9 KB (padded stride 144B)
  const int bh = blockIdx.x, pp = blockIdx.y;
  const int b = bh >> 4, h = bh & 15;
  const int w = threadIdx.x >> 6, lane = threadIdx.x & 63;
  const int lr = lane & 15, lg = lane >> 4;
  const float slope = exp2f(-0.5f * (float)(h + 1));
  const __hip_bfloat16* Kbase = QKV + (size_t)b * Tc * NQ + Cc + h * Dc;
  const __hip_bfloat16* Vbase = Vt + (size_t)bh * Dc * Tc;
  const int krow = (lane >> 4);
  const int kcolb = ((lane & 15) << 4);
  const int vrow = (lane >> 3);
  const int vcolb = ((lane & 7) << 4);
  f32x4 zero = {0.f, 0.f, 0.f, 0.f};

  int buf = 0;
  for (int ti = 0; ti < 2; ti++) {
    const int qt = (ti == 0) ? (31 - pp) : pp;
    const int q0 = qt * 64 + w * 16;
    const int nchunk = qt + 1;
    bf16x8 aq[4];
    {
      const __hip_bfloat16* qb = QKV + (size_t)(b * Tc + q0 + lr) * NQ + h * Dc + lg * 8;
      for (int c = 0; c < 4; c++) aq[c] = *(const bf16x8*)(qb + c * 32);
    }
    f32x4 acc[8];
    for (int d = 0; d < 8; d++) acc[d] = zero;
    float mrow[4] = {-1e30f, -1e30f, -1e30f, -1e30f};
    float lrow[4] = {0.f, 0.f, 0.f, 0.f};

#define STAGE(bb, t)                                                              \
    {                                                                             \
      const int s0_ = (t) * 64;                                                   \
      for (int j = 0; j < 4; j++) {                                               \
        int row = w * 16 + j * 4 + krow;                                          \
        int cb = kcolb ^ ((row & 7) << 4);                                        \
        gload16(Kbase + (size_t)(s0_ + row) * NQ + (cb >> 1),                     \
                &Ks[bb][w * 16 + j * 4][0]);                                      \
      }                                                                           \
      for (int j = 0; j < 4; j++) {                                               \
        int row = w * 32 + j * 8 + vrow;                                          \
        int cb = vcolb ^ ((row & 7) << 4);                                        \
        gload16(Vbase + (size_t)row * Tc + s0_ + (cb >> 1),                       \
                &Vs[bb][w * 32 + j * 8][0]);                                      \
      }                                                                           \
    }

    STAGE(buf, 0);
    __syncthreads();
    for (int t = 0; t < nchunk; t++) {
      if (t + 1 < nchunk) STAGE(buf ^ 1, t + 1);
      const int s0 = t * 64;
      f32x4 s[4];
      for (int ss = 0; ss < 4; ss++) s[ss] = zero;
      __builtin_amdgcn_s_setprio(1);
      for (int c = 0; c < 4; c++)
        for (int ss = 0; ss < 4; ss++) {
          int kr = ss * 16 + lr;
          const bf16x8 kf = *(const bf16x8*)
              &Ks[buf][kr][((c * 64 + lg * 16) ^ ((kr & 7) << 4)) >> 1];
          s[ss] = mfma16(aq[c], kf, s[ss]);
        }
      __builtin_amdgcn_s_setprio(0);
      float ps[4][4], mt[4];
      for (int r = 0; r < 4; r++) mt[r] = -1e30f;
      for (int ss = 0; ss < 4; ss++) {
        int jj = s0 + ss * 16 + lr;
        for (int r = 0; r < 4; r++) {
          int i = q0 + lg * 4 + r;
          float pv = (jj <= i) ? s[ss][r] - slope * (float)(i - jj) : -1e30f;
          ps[ss][r] = pv;
          mt[r] = fmaxf(mt[r], pv);
        }
      }
      for (int m = 1; m < 16; m <<= 1)
        for (int r = 0; r < 4; r++) mt[r] = fmaxf(mt[r], __shfl_xor(mt[r], m));
      float corr[4], rs[4];
      for (int r = 0; r < 4; r++) {
        float mn = fmaxf(mrow[r], mt[r]);
        corr[r] = __expf(mrow[r] - mn);
        mrow[r] = mn;
        rs[r] = 0.f;
      }
      for (int ss = 0; ss < 4; ss++)
        for (int r = 0; r < 4; r++) {
          float e = __expf(ps[ss][r] - mrow[r]);
          ps[ss][r] = e;
          rs[r] += e;
        }
      for (int m = 1; m < 16; m <<= 1)
        for (int r = 0; r < 4; r++) rs[r] += __shfl_xor(rs[r], m);
      for (int r = 0; r < 4; r++) lrow[r] = lrow[r] * corr[r] + rs[r];
      for (int d = 0; d < 8; d++)
        for (int r = 0; r < 4; r++) acc[d][r] *= corr[r];
      for (int ss = 0; ss < 4; ss++)
        for (int r = 0; r < 4; r++)
          Plds[w][lg * 4 + r][ss * 16 + lr] = __float2bfloat16(ps[ss][r]);
      bf16x8 pa0 = *(const bf16x8*)&Plds[w][lr][lg * 8];
      bf16x8 pa1 = *(const bf16x8*)&Plds[w][lr][32 + lg * 8];
      __builtin_amdgcn_s_setprio(1);
      for (int d = 0; d < 8; d++) {
        int vr = d * 16 + lr;
        const bf16x8 b0 = *(const bf16x8*)
            &Vs[buf][vr][((lg * 16) ^ ((vr & 7) << 4)) >> 1];
        const bf16x8 b1 = *(const bf16x8*)
            &Vs[buf][vr][((64 + lg * 16) ^ ((vr & 7) << 4)) >> 1];
        acc[d] = mfma16(pa0, b0, acc[d]);
        acc[d] = mfma16(pa1, b1, acc[d]);
      }
      __builtin_amdgcn_s_setprio(0);
      __syncthreads();
      buf ^= 1;
    }
#undef STAGE
    float ssum[4] = {0.f, 0.f, 0.f, 0.f};
    for (int r = 0; r < 4; r++) {
      float rl = 1.0f / lrow[r];
      for (int d = 0; d < 8; d++) {
        float o = acc[d][r] * rl;
        acc[d][r] = o;
        ssum[r] += o * o;
      }
    }
    for (int m = 1; m < 16; m <<= 1)
      for (int r = 0; r < 4; r++) ssum[r] += __shfl_xor(ssum[r], m);
    float ms[4];
    for (int r = 0; r < 4; r++) ms[r] = rsqrtf(ssum[r] * (1.0f / Dc) + EPSc);
    for (int d = 0; d < 8; d++) {
      float wv = subw[d * 16 + lr];
      for (int r = 0; r < 4; r++) {
        float y = acc[d][r] * ms[r] * wv;
        Y[(size_t)(b * Tc + q0 + lg * 4 + r) * Cc + h * Dc + d * 16 + lr] =
            __float2bfloat16(y);
      }
    }
  }
}

extern "C" void kernel_launch(void* const* d_in, const int* in_sizes, int n_in,
                              void* d_out, int out_size, void* d_ws, size_t ws_size,
                              hipStream_t stream) {
  const float* x  = (const float*)d_in[0];
  const float* Wq = (const float*)d_in[1];
  const float* Wk = (const float*)d_in[2];
  const float* Wv = (const float*)d_in[3];
  const float* Wp = (const float*)d_in[4];
  const float* qw = (const float*)d_in[5];
  const float* kw = (const float*)d_in[6];
  const float* sw = (const float*)d_in[7];
  float* out = (float*)d_out;

  char* ws = (char*)d_ws;
  __hip_bfloat16* Xb    = (__hip_bfloat16*)(ws + 0);          // 16 MiB (4096x2048)
  __hip_bfloat16* Wqkv  = (__hip_bfloat16*)(ws + 16777216);   // 24 MiB (6144x2048, N-major)
  __hip_bfloat16* Wproj = (__hip_bfloat16*)(ws + 41943040);   //  8 MiB (2048x2048, N-major)
  __hip_bfloat16* QKV   = (__hip_bfloat16*)(ws + 50331648);   // 48 MiB (4096x6144)
  __hip_bfloat16* Vt    = (__hip_bfloat16*)(ws + 100663296);  // 16 MiB (b,h,d,t)
  __hip_bfloat16* Yb    = (__hip_bfloat16*)(ws + 117440512);  // 16 MiB (4096x2048)

  k_xconv<<<dim3((BTc * Cc) / 1024), 256, 0, stream>>>(x, Xb);
  k_wconv<<<dim3(32, 32, 4), 256, 0, stream>>>(Wq, Wk, Wv, Wp, Wqkv, Wproj);
  k_gemm8<__hip_bfloat16><<<dim3((BTc / 256) * (NQ / 256)), 512, 0, stream>>>(
      Xb, Wqkv, QKV, BTc, NQ, Cc);
  k_qkrms<<<dim3(BTc, 8), 256, 0, stream>>>(QKV, qw, kw);
  k_vtrans<<<dim3(Tc / 64, Dc / 64, Bc * Hc), 256, 0, stream>>>(QKV, Vt);
  k_attn<<<dim3(Bc * Hc, 16), 256, 0, stream>>>(QKV, Vt, sw, Yb);
  k_gemm8<float><<<dim3((BTc / 256) * (Cc / 256)), 512, 0, stream>>>(
      Yb, Wproj, out, BTc, Cc, Cc);
}

// Round 5
// 299.012 us; speedup vs baseline: 1.1176x; 1.0709x over previous
//
#include <hip/hip_runtime.h>
#include <hip/hip_bf16.h>

// Problem constants
#define Bc 2
#define Tc 2048
#define Cc 2048
#define Hc 16
#define Dc 128
#define BTc 4096
#define NQ 6144            // 3*Cc
#define EPSc 1e-5f
#define QSCALE 0.08838834764831845f   // 1/sqrt(128)

typedef __attribute__((ext_vector_type(8))) short bf16x8;
typedef __attribute__((ext_vector_type(4))) short bf16x4;
typedef __attribute__((ext_vector_type(4))) float f32x4;

__device__ __forceinline__ f32x4 mfma16(bf16x8 a, bf16x8 b, f32x4 c) {
  return __builtin_amdgcn_mfma_f32_16x16x32_bf16(a, b, c, 0, 0, 0);
}

__device__ __forceinline__ void gload16(const void* g, void* l) {
  __builtin_amdgcn_global_load_lds(
      (const __attribute__((address_space(1))) void*)g,
      (__attribute__((address_space(3))) void*)l, 16, 0, 0);
}

// ---------------- fp32 -> bf16 convert (x) ----------------
__global__ __launch_bounds__(256) void k_xconv(const float* __restrict__ x,
                                               __hip_bfloat16* __restrict__ xb) {
  size_t i = ((size_t)blockIdx.x * 256 + threadIdx.x) * 4;
  float4 v = *(const float4*)(x + i);
  union { __hip_bfloat16 h[4]; bf16x4 v4; } u;
  u.h[0] = __float2bfloat16(v.x); u.h[1] = __float2bfloat16(v.y);
  u.h[2] = __float2bfloat16(v.z); u.h[3] = __float2bfloat16(v.w);
  *(bf16x4*)(xb + i) = u.v4;
}

// ------- weight transpose+convert: W (K x N) fp32 -> Wt (N x K) bf16 -------
__global__ __launch_bounds__(256) void k_wconv(const float* __restrict__ Wq,
    const float* __restrict__ Wk, const float* __restrict__ Wv,
    const float* __restrict__ Wp, __hip_bfloat16* __restrict__ Wqkv_t,
    __hip_bfloat16* __restrict__ Wproj_t) {
  __shared__ float tile[64][65];
  int z = blockIdx.z;
  const float* src = (z == 0) ? Wq : (z == 1) ? Wk : (z == 2) ? Wv : Wp;
  __hip_bfloat16* dst = (z < 3) ? (Wqkv_t + (size_t)z * Cc * Cc) : Wproj_t;
  int k0 = blockIdx.x * 64, n0 = blockIdx.y * 64;
  int c = threadIdx.x & 63, rb = threadIdx.x >> 6;
  for (int i = 0; i < 16; i++) {
    int r = rb * 16 + i;
    tile[r][c] = src[(size_t)(k0 + r) * Cc + n0 + c];
  }
  __syncthreads();
  for (int i = 0; i < 16; i++) {
    int r = rb * 16 + i;
    dst[(size_t)(n0 + r) * Cc + k0 + c] = __float2bfloat16(tile[c][r]);
  }
}

// ============ 256x256 8-phase GEMM, m201-faithful port ======================
// C[m][n] = sum_k A[m][k]*Bt[n][k].  8 waves (2Mx4N), BK=64 per K-tile.
// LDS: 8 slots x 16KB; slot = 256 rows x 32 K-cols (one k-half of one
// matrix for one K-tile), rows of 64B with 16B-chunk XOR swizzle
// (chunk' = chunk ^ ((row>>1)&3)); staging pre-swizzles the GLOBAL column
// (dest linear, m173 pattern).  buf0 (even tiles): A@0,A@16K,B@32K,B@48K;
// buf1 (odd): +64K.
// Per iteration (2 K-tiles, 8 phases), quadrant order per tile:
// (m0-3,n0-1)(m4-7,n0-1)(m4-7,n2-3)(m0-3,n2-3) -> reads/phase 12,8,4,0.
// Each phase stages ONE slot into a region whose last ds_read was >=1
// closed phase earlier:
//   ph1:B(2i+1)k0  ph2:B(2i+1)k1  ph3:A(2i+2)k0  ph4:A(2i+2)k1
//   ph5:B(2i+2)k0  ph6:B(2i+2)k1  ph7:A(2i+3)k0  ph8:A(2i+3)k1
// vmcnt(4) at ph4 (covers A(2i+1)+B(2i+1) before ph5) and ph8 (covers
// tile 2i+2 before next ph1).  Phase body: reads; stage; barrier;
// lgkmcnt(0); sched_barrier(0); setprio(1); 16 MFMA; setprio(0); barrier.
__device__ __forceinline__ void rdA(bf16x8 (&d)[8], const char* base, int roff) {
#pragma unroll
  for (int m = 0; m < 4; m++)
#pragma unroll
    for (int kk = 0; kk < 2; kk++)
      d[m * 2 + kk] = *(const bf16x8*)(base + kk * 16384 + m * 1024 + roff);
}
__device__ __forceinline__ void rdB(bf16x8 (&d)[4], const char* base, int roff) {
#pragma unroll
  for (int n = 0; n < 2; n++)
#pragma unroll
    for (int kk = 0; kk < 2; kk++)
      d[n * 2 + kk] = *(const bf16x8*)(base + kk * 16384 + n * 1024 + roff);
}
template <int MB, int NB>
__device__ __forceinline__ void mmQ(f32x4 (&acc)[8][4], const bf16x8 (&A_)[8],
                                    const bf16x8 (&B_)[4]) {
  __builtin_amdgcn_s_setprio(1);
#pragma unroll
  for (int kk = 0; kk < 2; kk++)
#pragma unroll
    for (int m = 0; m < 4; m++)
#pragma unroll
    for (int n = 0; n < 2; n++)
      acc[MB * 4 + m][NB * 2 + n] =
          mfma16(A_[m * 2 + kk], B_[n * 2 + kk], acc[MB * 4 + m][NB * 2 + n]);
  __builtin_amdgcn_s_setprio(0);
}

template <typename OutT>
__global__ __launch_bounds__(512, 2) void k_gemm8(const __hip_bfloat16* __restrict__ A,
    const __hip_bfloat16* __restrict__ Bt, OutT* __restrict__ Co,
    int M, int N, int K) {
  __shared__ __align__(16) char lds[131072];
  const int nbx = M >> 8;
  const int nwg = nbx * (N >> 8);              // divisible by 8 for our shapes
  const int wg = blockIdx.x;
  const int swz = (wg & 7) * (nwg >> 3) + (wg >> 3);
  const int bx = swz % nbx, by = swz / nbx;
  const int tid = threadIdx.x, lane = tid & 63, wid = tid >> 6;
  const int wr = wid >> 2, wc = wid & 3;
  const int lr = lane & 15, lg = lane >> 4;
  const int roff = lr * 64 + (lg ^ ((lr >> 1) & 3)) * 16;
  // staging: thread covers rows srow, srow+128 at swizzled source column
  const int srow = wid * 16 + (lane >> 2);
  const int scol = (((lane & 3) ^ ((srow >> 1) & 3)) << 3);
  const __hip_bfloat16* Ag = A + (size_t)(bx * 256 + srow) * K + scol;
  const __hip_bfloat16* Bg = Bt + (size_t)(by * 256 + srow) * K + scol;
  char* ldsw = lds + wid * 1024;
  const size_t rstep = (size_t)128 * K;
  const char* bA0 = lds;
  const char* bB0 = lds + 32768;
  const char* bA1 = lds + 65536;
  const char* bB1 = lds + 98304;

#define STG(slotoff, gp, t, ks) { const __hip_bfloat16* g_ = (gp) + (t) * 64 + (ks) * 32; \
    gload16(g_, ldsw + (slotoff)); gload16(g_ + rstep, ldsw + (slotoff) + 8192); }
#define BARRIER __builtin_amdgcn_s_barrier()
#define VW4 asm volatile("s_waitcnt vmcnt(4)" ::: "memory")
#define LGKM0 asm volatile("s_waitcnt lgkmcnt(0)" ::: "memory")
#define SB0 __builtin_amdgcn_sched_barrier(0)

  f32x4 acc[8][4];
#pragma unroll
  for (int m = 0; m < 8; m++)
#pragma unroll
    for (int n = 0; n < 4; n++) acc[m][n] = f32x4{0.f, 0.f, 0.f, 0.f};
  bf16x8 rAlo[8], rAhi[8], rB0[4], rB1[4];

  const int NT = K >> 6, NIT = K >> 7;   // NT even
  // prologue: tile0 all 4 slots + tile1 A slots (B(1) staged at ph1/ph2)
  STG(0, Ag, 0, 0); STG(16384, Ag, 0, 1);
  STG(32768, Bg, 0, 0); STG(49152, Bg, 0, 1);
  STG(65536, Ag, 1, 0); STG(81920, Ag, 1, 1);
  VW4;            // tile0 landed; tile1-A may be outstanding
  BARRIER;

  for (int it = 0; it < NIT; ++it) {
    const int tb = 2 * it + 1;
    const int tn2 = (2 * it + 2 < NT) ? 2 * it + 2 : NT - 1;  // clamped last iter
    const int tn3 = (2 * it + 3 < NT) ? 2 * it + 3 : NT - 1;
    // ---- tile 2i from buf0 ----
    // ph1
    rdA(rAlo, bA0 + wr * 8192, roff);
    rdB(rB0, bB0 + wc * 4096, roff);
    STG(98304, Bg, tb, 0);
    BARRIER; LGKM0; SB0;
    mmQ<0, 0>(acc, rAlo, rB0);
    BARRIER;
    // ph2
    rdA(rAhi, bA0 + wr * 8192 + 4096, roff);
    STG(114688, Bg, tb, 1);
    BARRIER; LGKM0; SB0;
    mmQ<1, 0>(acc, rAhi, rB0);
    BARRIER;
    // ph3
    rdB(rB1, bB0 + wc * 4096 + 2048, roff);
    STG(0, Ag, tn2, 0);
    BARRIER; LGKM0; SB0;
    mmQ<1, 1>(acc, rAhi, rB1);
    BARRIER;
    // ph4
    STG(16384, Ag, tn2, 1);
    BARRIER; SB0;
    mmQ<0, 1>(acc, rAlo, rB1);
    VW4;
    BARRIER;
    // ---- tile 2i+1 from buf1 ----
    // ph5
    rdA(rAlo, bA1 + wr * 8192, roff);
    rdB(rB0, bB1 + wc * 4096, roff);
    STG(32768, Bg, tn2, 0);
    BARRIER; LGKM0; SB0;
    mmQ<0, 0>(acc, rAlo, rB0);
    BARRIER;
    // ph6
    rdA(rAhi, bA1 + wr * 8192 + 4096, roff);
    STG(49152, Bg, tn2, 1);
    BARRIER; LGKM0; SB0;
    mmQ<1, 0>(acc, rAhi, rB0);
    BARRIER;
    // ph7
    rdB(rB1, bB1 + wc * 4096 + 2048, roff);
    STG(65536, Ag, tn3, 0);
    BARRIER; LGKM0; SB0;
    mmQ<1, 1>(acc, rAhi, rB1);
    BARRIER;
    // ph8
    STG(81920, Ag, tn3, 1);
    BARRIER; SB0;
    mmQ<0, 1>(acc, rAlo, rB1);
    VW4;
    BARRIER;
  }
#undef STG

  const int row0 = bx * 256 + wr * 128 + lg * 4;
  const int col0 = by * 256 + wc * 64 + lr;
#pragma unroll
  for (int m = 0; m < 8; m++)
#pragma unroll
    for (int n = 0; n < 4; n++) {
      size_t base = (size_t)(row0 + m * 16) * N + col0 + n * 16;
#pragma unroll
      for (int r = 0; r < 4; r++) {
        float v = acc[m][n][r];
        if constexpr (sizeof(OutT) == 2)
          Co[base + (size_t)r * N] = __float2bfloat16(v);
        else
          Co[base + (size_t)r * N] = v;
      }
    }
}

// ---------------- in-place QK RMSNorm over head dim (D=128) ----------------
__global__ __launch_bounds__(256) void k_qkrms(__hip_bfloat16* __restrict__ QKV,
    const float* __restrict__ qw, const float* __restrict__ kw) {
  int bt = blockIdx.x;
  int w = threadIdx.x >> 6, lane = threadIdx.x & 63;
  int hv = blockIdx.y * 4 + w;
  const float* wt; int col; float extra;
  if (hv < 16) { wt = qw; col = hv * Dc;             extra = QSCALE; }
  else         { wt = kw; col = Cc + (hv - 16) * Dc; extra = 1.0f;   }
  __hip_bfloat16* p = QKV + (size_t)bt * NQ + col + lane * 2;
  float x0 = __bfloat162float(p[0]);
  float x1 = __bfloat162float(p[1]);
  float ss = x0 * x0 + x1 * x1;
  for (int m = 1; m < 64; m <<= 1) ss += __shfl_xor(ss, m);
  float sc = rsqrtf(ss * (1.0f / Dc) + EPSc) * extra;
  p[0] = __float2bfloat16(x0 * sc * wt[lane * 2]);
  p[1] = __float2bfloat16(x1 * sc * wt[lane * 2 + 1]);
}

// ---------------- V transpose: (b,t,h,d) cols of QKV -> Vt (b,h,d,t) -------
__global__ __launch_bounds__(256) void k_vtrans(const __hip_bfloat16* __restrict__ QKV,
                                                __hip_bfloat16* __restrict__ Vt) {
  __shared__ __hip_bfloat16 tile[64][65];
  int bh = blockIdx.z, t0 = blockIdx.x * 64, d0 = blockIdx.y * 64;
  int b = bh >> 4, h = bh & 15;
  int c = threadIdx.x & 63, rb = threadIdx.x >> 6;
  for (int i = 0; i < 16; i++) {
    int r = rb * 16 + i;
    tile[r][c] = QKV[(size_t)(b * Tc + t0 + r) * NQ + 2 * Cc + h * Dc + d0 + c];
  }
  __syncthreads();
  for (int i = 0; i < 16; i++) {
    int r = rb * 16 + i;
    Vt[((size_t)bh * Dc + d0 + r) * Tc + t0 + c] = tile[c][r];
  }
}

// ---------------- flash attention v2: LDS-staged K/V, dbuf, paired tiles ---
// grid (bh=32, pp=16); 4 waves; block handles q-tiles {31-pp, pp} (64 rows each)
__global__ __launch_bounds__(256, 2) void k_attn(const __hip_bfloat16* __restrict__ QKV,
    const __hip_bfloat16* __restrict__ Vt, const float* __restrict__ subw,
    __hip_bfloat16* __restrict__ Y) {
  __shared__ __align__(16) __hip_bfloat16 Ks[2][64][128];   // 32 KB
  __shared__ __align__(16) __hip_bfloat16 Vs[2][128][64];   // 32 KB
  __shared__ __align__(16) __hip_bfloat16 Plds[4][16][72];  // 9 KB (padded stride 144B)
  const int bh = blockIdx.x, pp = blockIdx.y;
  const int b = bh >> 4, h = bh & 15;
  const int w = threadIdx.x >> 6, lane = threadIdx.x & 63;
  const int lr = lane & 15, lg = lane >> 4;
  const float slope = exp2f(-0.5f * (float)(h + 1));
  const __hip_bfloat16* Kbase = QKV + (size_t)b * Tc * NQ + Cc + h * Dc;
  const __hip_bfloat16* Vbase = Vt + (size_t)bh * Dc * Tc;
  const int krow = (lane >> 4);
  const int kcolb = ((lane & 15) << 4);
  const int vrow = (lane >> 3);
  const int vcolb = ((lane & 7) << 4);
  f32x4 zero = {0.f, 0.f, 0.f, 0.f};

  int buf = 0;
  for (int ti = 0; ti < 2; ti++) {
    const int qt = (ti == 0) ? (31 - pp) : pp;
    const int q0 = qt * 64 + w * 16;
    const int nchunk = qt + 1;
    bf16x8 aq[4];
    {
      const __hip_bfloat16* qb = QKV + (size_t)(b * Tc + q0 + lr) * NQ + h * Dc + lg * 8;
      for (int c = 0; c < 4; c++) aq[c] = *(const bf16x8*)(qb + c * 32);
    }
    f32x4 acc[8];
    for (int d = 0; d < 8; d++) acc[d] = zero;
    float mrow[4] = {-1e30f, -1e30f, -1e30f, -1e30f};
    float lrow[4] = {0.f, 0.f, 0.f, 0.f};

#define STAGE(bb, t)                                                              \
    {                                                                             \
      const int s0_ = (t) * 64;                                                   \
      for (int j = 0; j < 4; j++) {                                               \
        int row = w * 16 + j * 4 + krow;                                          \
        int cb = kcolb ^ ((row & 7) << 4);                                        \
        gload16(Kbase + (size_t)(s0_ + row) * NQ + (cb >> 1),                     \
                &Ks[bb][w * 16 + j * 4][0]);                                      \
      }                                                                           \
      for (int j = 0; j < 4; j++) {                                               \
        int row = w * 32 + j * 8 + vrow;                                          \
        int cb = vcolb ^ ((row & 7) << 4);                                        \
        gload16(Vbase + (size_t)row * Tc + s0_ + (cb >> 1),                       \
                &Vs[bb][w * 32 + j * 8][0]);                                      \
      }                                                                           \
    }

    STAGE(buf, 0);
    __syncthreads();
    for (int t = 0; t < nchunk; t++) {
      if (t + 1 < nchunk) STAGE(buf ^ 1, t + 1);
      const int s0 = t * 64;
      f32x4 s[4];
      for (int ss = 0; ss < 4; ss++) s[ss] = zero;
      __builtin_amdgcn_s_setprio(1);
      for (int c = 0; c < 4; c++)
        for (int ss = 0; ss < 4; ss++) {
          int kr = ss * 16 + lr;
          const bf16x8 kf = *(const bf16x8*)
              &Ks[buf][kr][((c * 64 + lg * 16) ^ ((kr & 7) << 4)) >> 1];
          s[ss] = mfma16(aq[c], kf, s[ss]);
        }
      __builtin_amdgcn_s_setprio(0);
      float ps[4][4], mt[4];
      for (int r = 0; r < 4; r++) mt[r] = -1e30f;
      for (int ss = 0; ss < 4; ss++) {
        int jj = s0 + ss * 16 + lr;
        for (int r = 0; r < 4; r++) {
          int i = q0 + lg * 4 + r;
          float pv = (jj <= i) ? s[ss][r] - slope * (float)(i - jj) : -1e30f;
          ps[ss][r] = pv;
          mt[r] = fmaxf(mt[r], pv);
        }
      }
      for (int m = 1; m < 16; m <<= 1)
        for (int r = 0; r < 4; r++) mt[r] = fmaxf(mt[r], __shfl_xor(mt[r], m));
      float corr[4], rs[4];
      for (int r = 0; r < 4; r++) {
        float mn = fmaxf(mrow[r], mt[r]);
        corr[r] = __expf(mrow[r] - mn);
        mrow[r] = mn;
        rs[r] = 0.f;
      }
      for (int ss = 0; ss < 4; ss++)
        for (int r = 0; r < 4; r++) {
          float e = __expf(ps[ss][r] - mrow[r]);
          ps[ss][r] = e;
          rs[r] += e;
        }
      for (int m = 1; m < 16; m <<= 1)
        for (int r = 0; r < 4; r++) rs[r] += __shfl_xor(rs[r], m);
      for (int r = 0; r < 4; r++) lrow[r] = lrow[r] * corr[r] + rs[r];
      for (int d = 0; d < 8; d++)
        for (int r = 0; r < 4; r++) acc[d][r] *= corr[r];
      for (int ss = 0; ss < 4; ss++)
        for (int r = 0; r < 4; r++)
          Plds[w][lg * 4 + r][ss * 16 + lr] = __float2bfloat16(ps[ss][r]);
      bf16x8 pa0 = *(const bf16x8*)&Plds[w][lr][lg * 8];
      bf16x8 pa1 = *(const bf16x8*)&Plds[w][lr][32 + lg * 8];
      __builtin_amdgcn_s_setprio(1);
      for (int d = 0; d < 8; d++) {
        int vr = d * 16 + lr;
        const bf16x8 b0 = *(const bf16x8*)
            &Vs[buf][vr][((lg * 16) ^ ((vr & 7) << 4)) >> 1];
        const bf16x8 b1 = *(const bf16x8*)
            &Vs[buf][vr][((64 + lg * 16) ^ ((vr & 7) << 4)) >> 1];
        acc[d] = mfma16(pa0, b0, acc[d]);
        acc[d] = mfma16(pa1, b1, acc[d]);
      }
      __builtin_amdgcn_s_setprio(0);
      __syncthreads();
      buf ^= 1;
    }
#undef STAGE
    float ssum[4] = {0.f, 0.f, 0.f, 0.f};
    for (int r = 0; r < 4; r++) {
      float rl = 1.0f / lrow[r];
      for (int d = 0; d < 8; d++) {
        float o = acc[d][r] * rl;
        acc[d][r] = o;
        ssum[r] += o * o;
      }
    }
    for (int m = 1; m < 16; m <<= 1)
      for (int r = 0; r < 4; r++) ssum[r] += __shfl_xor(ssum[r], m);
    float ms[4];
    for (int r = 0; r < 4; r++) ms[r] = rsqrtf(ssum[r] * (1.0f / Dc) + EPSc);
    for (int d = 0; d < 8; d++) {
      float wv = subw[d * 16 + lr];
      for (int r = 0; r < 4; r++) {
        float y = acc[d][r] * ms[r] * wv;
        Y[(size_t)(b * Tc + q0 + lg * 4 + r) * Cc + h * Dc + d * 16 + lr] =
            __float2bfloat16(y);
      }
    }
  }
}

extern "C" void kernel_launch(void* const* d_in, const int* in_sizes, int n_in,
                              void* d_out, int out_size, void* d_ws, size_t ws_size,
                              hipStream_t stream) {
  const float* x  = (const float*)d_in[0];
  const float* Wq = (const float*)d_in[1];
  const float* Wk = (const float*)d_in[2];
  const float* Wv = (const float*)d_in[3];
  const float* Wp = (const float*)d_in[4];
  const float* qw = (const float*)d_in[5];
  const float* kw = (const float*)d_in[6];
  const float* sw = (const float*)d_in[7];
  float* out = (float*)d_out;

  char* ws = (char*)d_ws;
  __hip_bfloat16* Xb    = (__hip_bfloat16*)(ws + 0);          // 16 MiB (4096x2048)
  __hip_bfloat16* Wqkv  = (__hip_bfloat16*)(ws + 16777216);   // 24 MiB (6144x2048, N-major)
  __hip_bfloat16* Wproj = (__hip_bfloat16*)(ws + 41943040);   //  8 MiB (2048x2048, N-major)
  __hip_bfloat16* QKV   = (__hip_bfloat16*)(ws + 50331648);   // 48 MiB (4096x6144)
  __hip_bfloat16* Vt    = (__hip_bfloat16*)(ws + 100663296);  // 16 MiB (b,h,d,t)
  __hip_bfloat16* Yb    = (__hip_bfloat16*)(ws + 117440512);  // 16 MiB (4096x2048)

  k_xconv<<<dim3((BTc * Cc) / 1024), 256, 0, stream>>>(x, Xb);
  k_wconv<<<dim3(32, 32, 4), 256, 0, stream>>>(Wq, Wk, Wv, Wp, Wqkv, Wproj);
  k_gemm8<__hip_bfloat16><<<dim3((BTc / 256) * (NQ / 256)), 512, 0, stream>>>(
      Xb, Wqkv, QKV, BTc, NQ, Cc);
  k_qkrms<<<dim3(BTc, 8), 256, 0, stream>>>(QKV, qw, kw);
  k_vtrans<<<dim3(Tc / 64, Dc / 64, Bc * Hc), 256, 0, stream>>>(QKV, Vt);
  k_attn<<<dim3(Bc * Hc, 16), 256, 0, stream>>>(QKV, Vt, sw, Yb);
  k_gemm8<float><<<dim3((BTc / 256) * (Cc / 256)), 512, 0, stream>>>(
      Yb, Wproj, out, BTc, Cc, Cc);
}